// Round 1
// baseline (636.079 us; speedup 1.0000x reference)
//
#include <hip/hip_runtime.h>
#include <cstdint>
#include <cstddef>

#define NN 100000
#define NE 1600000
#define D 128

// ---------------- workspace layout (bytes) ----------------
// h     : NN*128 f32   @ 0          (51,200,000)
// z     : NN*2   f32   @ 51,200,000 (   800,000)
// dinv  : NN     f32   @ 52,000,000 (   400,000)
// cnt   : NN     u32   @ 52,400,000 (   400,000)
// fill  : NN     u32   @ 52,800,000 (   400,000)
// rp    : NN+1   u32   @ 53,200,000 (   400,004 -> pad 16)
// col   : NE     u32   @ 53,600,016 ( 6,400,000)
// bsum  : 128    u32   @ 60,000,016 (       512)
// total ~60.0 MB

__global__ void hist_k(const int* __restrict__ ei, unsigned* __restrict__ cnt) {
    int e = blockIdx.x * 256 + threadIdx.x;
    if (e < NE) atomicAdd(&cnt[ei[NE + e]], 1u);
}

__global__ void dinv_k(const unsigned* __restrict__ cnt, float* __restrict__ dinv) {
    int i = blockIdx.x * 256 + threadIdx.x;
    if (i < NN) dinv[i] = rsqrtf((float)(cnt[i] + 1u));
}

// exclusive scan of cnt -> rp, block partials -> bsum. 1024 elems / block.
__global__ void scan1_k(const unsigned* __restrict__ cnt, unsigned* __restrict__ rp,
                        unsigned* __restrict__ bsum) {
    __shared__ unsigned sh[256];
    int t = threadIdx.x;
    int base = blockIdx.x * 1024 + t * 4;
    unsigned v0 = (base + 0 < NN) ? cnt[base + 0] : 0u;
    unsigned v1 = (base + 1 < NN) ? cnt[base + 1] : 0u;
    unsigned v2 = (base + 2 < NN) ? cnt[base + 2] : 0u;
    unsigned v3 = (base + 3 < NN) ? cnt[base + 3] : 0u;
    unsigned sum = v0 + v1 + v2 + v3;
    sh[t] = sum;
    __syncthreads();
    for (int off = 1; off < 256; off <<= 1) {
        unsigned u = (t >= off) ? sh[t - off] : 0u;
        __syncthreads();
        sh[t] += u;
        __syncthreads();
    }
    unsigned excl = sh[t] - sum;
    if (base + 0 < NN) rp[base + 0] = excl; excl += v0;
    if (base + 1 < NN) rp[base + 1] = excl; excl += v1;
    if (base + 2 < NN) rp[base + 2] = excl; excl += v2;
    if (base + 3 < NN) rp[base + 3] = excl;
    if (t == 255) bsum[blockIdx.x] = sh[255];
}

__global__ void scan2_k(unsigned* __restrict__ bsum, int nb) {
    __shared__ unsigned sh[128];
    int t = threadIdx.x;
    unsigned v = (t < nb) ? bsum[t] : 0u;
    sh[t] = v;
    __syncthreads();
    for (int off = 1; off < 128; off <<= 1) {
        unsigned u = (t >= off) ? sh[t - off] : 0u;
        __syncthreads();
        sh[t] += u;
        __syncthreads();
    }
    if (t < nb) bsum[t] = sh[t] - v;  // exclusive
}

__global__ void scan3_k(unsigned* __restrict__ rp, const unsigned* __restrict__ bsum) {
    int i = blockIdx.x * 256 + threadIdx.x;
    if (i < NN) rp[i] += bsum[i >> 10];
    if (i == 0) rp[NN] = NE;
}

__global__ void fill_k(const int* __restrict__ ei, const unsigned* __restrict__ rp,
                       unsigned* __restrict__ fill, unsigned* __restrict__ col) {
    int e = blockIdx.x * 256 + threadIdx.x;
    if (e < NE) {
        int s = ei[e];
        int d = ei[NE + e];
        unsigned pos = rp[d] + atomicAdd(&fill[d], 1u);
        col[pos] = (unsigned)s;
    }
}

__device__ inline void fma4(float4& a, float s, const float4& w) {
    a.x += s * w.x; a.y += s * w.y; a.z += s * w.z; a.w += s * w.w;
}

// h = x @ W1.  Block: 256 threads = 16 colgroups x 16 rowgroups; tile 128 rows x 128 cols.
// Each thread: 8 rows x 8 cols = 64 fp32 accumulators.  W1 (64KB) L1/L2-resident.
__launch_bounds__(256)
__global__ void gemm1_k(const float* __restrict__ x, const float* __restrict__ W,
                        float* __restrict__ h) {
    int tid = threadIdx.x;
    int cg = tid >> 4;          // 0..15
    int rg = tid & 15;          // 0..15
    int j0 = cg * 8;
    int rb = blockIdx.x * 128;

    float4 acc[8][2];
#pragma unroll
    for (int i = 0; i < 8; i++) { acc[i][0] = make_float4(0,0,0,0); acc[i][1] = make_float4(0,0,0,0); }

    int r[8]; bool ok[8];
#pragma unroll
    for (int i = 0; i < 8; i++) { r[i] = rb + rg + 16 * i; ok[i] = (r[i] < NN); }

    for (int kk = 0; kk < D; kk += 4) {
        float4 xv[8];
#pragma unroll
        for (int i = 0; i < 8; i++)
            xv[i] = ok[i] ? *(const float4*)(x + (size_t)r[i] * D + kk) : make_float4(0,0,0,0);
        float4 wv[4][2];
#pragma unroll
        for (int t = 0; t < 4; t++) {
            wv[t][0] = *(const float4*)(W + (size_t)(kk + t) * D + j0);
            wv[t][1] = *(const float4*)(W + (size_t)(kk + t) * D + j0 + 4);
        }
#pragma unroll
        for (int i = 0; i < 8; i++) {
#pragma unroll
            for (int c = 0; c < 2; c++) {
                fma4(acc[i][c], xv[i].x, wv[0][c]);
                fma4(acc[i][c], xv[i].y, wv[1][c]);
                fma4(acc[i][c], xv[i].z, wv[2][c]);
                fma4(acc[i][c], xv[i].w, wv[3][c]);
            }
        }
    }
#pragma unroll
    for (int i = 0; i < 8; i++) {
        if (ok[i]) {
            *(float4*)(h + (size_t)r[i] * D + j0)     = acc[i][0];
            *(float4*)(h + (size_t)r[i] * D + j0 + 4) = acc[i][1];
        }
    }
}

// Layer-1 aggregation fused with bias+ReLU and the 128x2 layer-2 linear.
// One wave per node; lane holds float2 of the 128-wide row.
__launch_bounds__(256)
__global__ void agg1_k(const float* __restrict__ h, const unsigned* __restrict__ rp,
                       const unsigned* __restrict__ col, const float* __restrict__ dinv,
                       const float* __restrict__ b1, const float* __restrict__ W2,
                       float* __restrict__ z) {
    int i = (blockIdx.x * 256 + threadIdx.x) >> 6;
    int lane = threadIdx.x & 63;
    if (i >= NN) return;

    float di = dinv[i];
    float2 hv = ((const float2*)(h + (size_t)i * D))[lane];
    float cself = di * di;
    float ax = cself * hv.x;
    float ay = cself * hv.y;

    unsigned p0 = rp[i], p1 = rp[i + 1];
    for (unsigned e = p0; e < p1; ++e) {
        unsigned s = col[e];
        float cf = di * dinv[s];
        float2 v = ((const float2*)(h + (size_t)s * D))[lane];
        ax += cf * v.x;
        ay += cf * v.y;
    }

    float2 bv = ((const float2*)b1)[lane];
    float h0 = fmaxf(ax + bv.x, 0.f);
    float h1 = fmaxf(ay + bv.y, 0.f);

    // z[i] = h2_row @ W2 ; lane covers feature d = 2*lane, 2*lane+1
    float4 w = ((const float4*)W2)[lane];  // W2[2l][0], W2[2l][1], W2[2l+1][0], W2[2l+1][1]
    float pz0 = h0 * w.x + h1 * w.z;
    float pz1 = h0 * w.y + h1 * w.w;
#pragma unroll
    for (int off = 32; off > 0; off >>= 1) {
        pz0 += __shfl_down(pz0, off);
        pz1 += __shfl_down(pz1, off);
    }
    if (lane == 0) {
        float2* zp = (float2*)(z + (size_t)i * 2);
        *zp = make_float2(pz0, pz1);
    }
}

// Layer-2 aggregation over z (N x 2, L2-resident). One wave per node, lanes over edges.
__launch_bounds__(256)
__global__ void agg2_k(const float* __restrict__ z, const unsigned* __restrict__ rp,
                       const unsigned* __restrict__ col, const float* __restrict__ dinv,
                       const float* __restrict__ b2, float* __restrict__ out) {
    int i = (blockIdx.x * 256 + threadIdx.x) >> 6;
    int lane = threadIdx.x & 63;
    if (i >= NN) return;

    float di = dinv[i];
    unsigned p0 = rp[i], p1 = rp[i + 1];
    float a0 = 0.f, a1 = 0.f;
    for (unsigned e = p0 + lane; e < p1; e += 64) {
        unsigned s = col[e];
        float cf = di * dinv[s];
        float2 v = ((const float2*)z)[s];
        a0 += cf * v.x;
        a1 += cf * v.y;
    }
#pragma unroll
    for (int off = 32; off > 0; off >>= 1) {
        a0 += __shfl_down(a0, off);
        a1 += __shfl_down(a1, off);
    }
    if (lane == 0) {
        float2 zi = ((const float2*)z)[i];
        out[(size_t)i * 2]     = a0 + di * di * zi.x + b2[0];
        out[(size_t)i * 2 + 1] = a1 + di * di * zi.y + b2[1];
    }
}

extern "C" void kernel_launch(void* const* d_in, const int* in_sizes, int n_in,
                              void* d_out, int out_size, void* d_ws, size_t ws_size,
                              hipStream_t stream) {
    const float* x  = (const float*)d_in[0];
    const int*   ei = (const int*)d_in[1];
    const float* W1 = (const float*)d_in[2];
    const float* b1 = (const float*)d_in[3];
    const float* W2 = (const float*)d_in[4];
    const float* b2 = (const float*)d_in[5];
    float* out = (float*)d_out;

    char* ws = (char*)d_ws;
    float*    h    = (float*)(ws);
    float*    z    = (float*)(ws + 51200000);
    float*    dinv = (float*)(ws + 52000000);
    unsigned* cnt  = (unsigned*)(ws + 52400000);
    unsigned* fill = (unsigned*)(ws + 52800000);
    unsigned* rp   = (unsigned*)(ws + 53200000);
    unsigned* col  = (unsigned*)(ws + 53600016);
    unsigned* bsum = (unsigned*)(ws + 60000016);

    hipMemsetAsync(cnt,  0, NN * sizeof(unsigned), stream);
    hipMemsetAsync(fill, 0, NN * sizeof(unsigned), stream);

    hist_k<<<(NE + 255) / 256, 256, 0, stream>>>(ei, cnt);
    dinv_k<<<(NN + 255) / 256, 256, 0, stream>>>(cnt, dinv);

    const int NB = (NN + 1023) / 1024;  // 98
    scan1_k<<<NB, 256, 0, stream>>>(cnt, rp, bsum);
    scan2_k<<<1, 128, 0, stream>>>(bsum, NB);
    scan3_k<<<(NN + 255) / 256, 256, 0, stream>>>(rp, bsum);

    fill_k<<<(NE + 255) / 256, 256, 0, stream>>>(ei, rp, fill, col);

    gemm1_k<<<(NN + 127) / 128, 256, 0, stream>>>(x, W1, h);
    agg1_k<<<(NN + 3) / 4, 256, 0, stream>>>(h, rp, col, dinv, b1, W2, z);
    agg2_k<<<(NN + 3) / 4, 256, 0, stream>>>(z, rp, col, dinv, b2, out);
}

// Round 2
// 479.617 us; speedup vs baseline: 1.3262x; 1.3262x over previous
//
#include <hip/hip_runtime.h>
#include <cstdint>
#include <cstddef>

#define NN 100000
#define NE 1600000
#define D 128

// ---------------- workspace layout (bytes) ----------------
// h     : NN*128 f32   @ 0          (51,200,000)
// z     : NN*2   f32   @ 51,200,000 (   800,000)
// dinv  : NN     f32   @ 52,000,000 (   400,000)
// cnt   : NN     u32   @ 52,400,000 (   400,000)
// fill  : NN     u32   @ 52,800,000 (   400,000)
// rp    : NN+1   u32   @ 53,200,000 (   400,004 -> pad 16)
// col   : NE     u32   @ 53,600,016 ( 6,400,000)
// bsum  : 128    u32   @ 60,000,016 (       512)
// total ~60.0 MB (fits the ws_size that round-1 already ran with)

__global__ void hist_k(const int* __restrict__ ei, unsigned* __restrict__ cnt) {
    int e = blockIdx.x * 256 + threadIdx.x;
    if (e < NE) atomicAdd(&cnt[ei[NE + e]], 1u);
}

__global__ void dinv_k(const unsigned* __restrict__ cnt, float* __restrict__ dinv) {
    int i = blockIdx.x * 256 + threadIdx.x;
    if (i < NN) dinv[i] = rsqrtf((float)(cnt[i] + 1u));
}

// exclusive scan of cnt -> rp, block partials -> bsum. 1024 elems / block.
__global__ void scan1_k(const unsigned* __restrict__ cnt, unsigned* __restrict__ rp,
                        unsigned* __restrict__ bsum) {
    __shared__ unsigned sh[256];
    int t = threadIdx.x;
    int base = blockIdx.x * 1024 + t * 4;
    unsigned v0 = (base + 0 < NN) ? cnt[base + 0] : 0u;
    unsigned v1 = (base + 1 < NN) ? cnt[base + 1] : 0u;
    unsigned v2 = (base + 2 < NN) ? cnt[base + 2] : 0u;
    unsigned v3 = (base + 3 < NN) ? cnt[base + 3] : 0u;
    unsigned sum = v0 + v1 + v2 + v3;
    sh[t] = sum;
    __syncthreads();
    for (int off = 1; off < 256; off <<= 1) {
        unsigned u = (t >= off) ? sh[t - off] : 0u;
        __syncthreads();
        sh[t] += u;
        __syncthreads();
    }
    unsigned excl = sh[t] - sum;
    if (base + 0 < NN) rp[base + 0] = excl; excl += v0;
    if (base + 1 < NN) rp[base + 1] = excl; excl += v1;
    if (base + 2 < NN) rp[base + 2] = excl; excl += v2;
    if (base + 3 < NN) rp[base + 3] = excl;
    if (t == 255) bsum[blockIdx.x] = sh[255];
}

__global__ void scan2_k(unsigned* __restrict__ bsum, int nb) {
    __shared__ unsigned sh[128];
    int t = threadIdx.x;
    unsigned v = (t < nb) ? bsum[t] : 0u;
    sh[t] = v;
    __syncthreads();
    for (int off = 1; off < 128; off <<= 1) {
        unsigned u = (t >= off) ? sh[t - off] : 0u;
        __syncthreads();
        sh[t] += u;
        __syncthreads();
    }
    if (t < nb) bsum[t] = sh[t] - v;  // exclusive
}

__global__ void scan3_k(unsigned* __restrict__ rp, const unsigned* __restrict__ bsum) {
    int i = blockIdx.x * 256 + threadIdx.x;
    if (i < NN) rp[i] += bsum[i >> 10];
    if (i == 0) rp[NN] = NE;
}

__global__ void fill_k(const int* __restrict__ ei, const unsigned* __restrict__ rp,
                       unsigned* __restrict__ fill, unsigned* __restrict__ col) {
    int e = blockIdx.x * 256 + threadIdx.x;
    if (e < NE) {
        int s = ei[e];
        int d = ei[NE + e];
        unsigned pos = rp[d] + atomicAdd(&fill[d], 1u);
        col[pos] = (unsigned)s;
    }
}

__device__ inline void fma4(float4& a, float s, const float4& w) {
    a.x = fmaf(s, w.x, a.x); a.y = fmaf(s, w.y, a.y);
    a.z = fmaf(s, w.z, a.z); a.w = fmaf(s, w.w, a.w);
}

// h = x @ W1.  Block: 256 threads; tile 128 rows x 128 cols.
// x tile staged through LDS in K-chunks of 32 (coalesced global loads);
// LDS row stride 36 floats -> 16B-aligned, 2-way bank aliasing only (free).
// Each thread: 8 rows x 8 cols fp32 accumulators. W1 via L1/L2 (broadcast pattern).
__launch_bounds__(256)
__global__ void gemm1_k(const float* __restrict__ x, const float* __restrict__ W,
                        float* __restrict__ h) {
    __shared__ float xs[128 * 36];
    int tid = threadIdx.x;
    int cg = tid >> 4;          // 0..15 -> column group
    int rg = tid & 15;          // 0..15 -> row within 16-row stripe
    int j0 = cg * 8;
    int rb = blockIdx.x * 128;

    float4 acc[8][2];
#pragma unroll
    for (int i = 0; i < 8; i++) { acc[i][0] = make_float4(0,0,0,0); acc[i][1] = make_float4(0,0,0,0); }

    for (int kk0 = 0; kk0 < D; kk0 += 32) {
        if (kk0) __syncthreads();
        // stage x[rb..rb+127][kk0..kk0+31] -> LDS, coalesced float4
#pragma unroll
        for (int q = 0; q < 4; q++) {
            int idx = q * 256 + tid;
            int row = idx >> 3;
            int c4  = (idx & 7) * 4;
            int gr  = rb + row;
            float4 v = (gr < NN) ? *(const float4*)(x + (size_t)gr * D + kk0 + c4)
                                 : make_float4(0,0,0,0);
            *(float4*)(&xs[row * 36 + c4]) = v;
        }
        __syncthreads();

#pragma unroll
        for (int kk = 0; kk < 32; kk += 4) {
            float4 xv[8];
#pragma unroll
            for (int i = 0; i < 8; i++)
                xv[i] = *(const float4*)(&xs[(rg + 16 * i) * 36 + kk]);
#pragma unroll
            for (int t = 0; t < 4; t++) {
                const float* wr = W + (size_t)(kk0 + kk + t) * D + j0;
                float4 w0 = *(const float4*)wr;
                float4 w1 = *(const float4*)(wr + 4);
#pragma unroll
                for (int i = 0; i < 8; i++) {
                    float s = (t == 0) ? xv[i].x : (t == 1) ? xv[i].y : (t == 2) ? xv[i].z : xv[i].w;
                    fma4(acc[i][0], s, w0);
                    fma4(acc[i][1], s, w1);
                }
            }
        }
    }

#pragma unroll
    for (int i = 0; i < 8; i++) {
        int r = rb + rg + 16 * i;
        if (r < NN) {
            *(float4*)(h + (size_t)r * D + j0)     = acc[i][0];
            *(float4*)(h + (size_t)r * D + j0 + 4) = acc[i][1];
        }
    }
}

// Layer-1 aggregation fused with bias+ReLU and the 128x2 layer-2 linear.
// One wave per node; lane holds float2 of the 128-wide row.
// Edge loop unrolled x4 so 4 row-gathers are in flight at once.
__launch_bounds__(256)
__global__ void agg1_k(const float* __restrict__ h, const unsigned* __restrict__ rp,
                       const unsigned* __restrict__ col, const float* __restrict__ dinv,
                       const float* __restrict__ b1, const float* __restrict__ W2,
                       float* __restrict__ z) {
    int i = (blockIdx.x * 256 + threadIdx.x) >> 6;
    int lane = threadIdx.x & 63;
    if (i >= NN) return;

    float di = dinv[i];
    float2 hv = ((const float2*)(h + (size_t)i * D))[lane];
    float cself = di * di;
    float ax = cself * hv.x;
    float ay = cself * hv.y;

    unsigned p0 = rp[i], p1 = rp[i + 1];
    unsigned e = p0;
    for (; e + 4 <= p1; e += 4) {
        unsigned s0 = col[e], s1 = col[e + 1], s2 = col[e + 2], s3 = col[e + 3];
        float d0 = dinv[s0], d1 = dinv[s1], d2 = dinv[s2], d3 = dinv[s3];
        float2 v0 = ((const float2*)(h + (size_t)s0 * D))[lane];
        float2 v1 = ((const float2*)(h + (size_t)s1 * D))[lane];
        float2 v2 = ((const float2*)(h + (size_t)s2 * D))[lane];
        float2 v3 = ((const float2*)(h + (size_t)s3 * D))[lane];
        ax = fmaf(di * d0, v0.x, ax); ay = fmaf(di * d0, v0.y, ay);
        ax = fmaf(di * d1, v1.x, ax); ay = fmaf(di * d1, v1.y, ay);
        ax = fmaf(di * d2, v2.x, ax); ay = fmaf(di * d2, v2.y, ay);
        ax = fmaf(di * d3, v3.x, ax); ay = fmaf(di * d3, v3.y, ay);
    }
    for (; e < p1; ++e) {
        unsigned s = col[e];
        float cf = di * dinv[s];
        float2 v = ((const float2*)(h + (size_t)s * D))[lane];
        ax = fmaf(cf, v.x, ax);
        ay = fmaf(cf, v.y, ay);
    }

    float2 bv = ((const float2*)b1)[lane];
    float h0 = fmaxf(ax + bv.x, 0.f);
    float h1 = fmaxf(ay + bv.y, 0.f);

    // z[i] = h2_row @ W2 ; lane covers feature d = 2*lane, 2*lane+1
    float4 w = ((const float4*)W2)[lane];  // W2[2l][0], W2[2l][1], W2[2l+1][0], W2[2l+1][1]
    float pz0 = fmaf(h0, w.x, h1 * w.z);
    float pz1 = fmaf(h0, w.y, h1 * w.w);
#pragma unroll
    for (int off = 32; off > 0; off >>= 1) {
        pz0 += __shfl_down(pz0, off);
        pz1 += __shfl_down(pz1, off);
    }
    if (lane == 0) {
        float2* zp = (float2*)(z + (size_t)i * 2);
        *zp = make_float2(pz0, pz1);
    }
}

// Layer-2 aggregation over z (N x 2, L2-resident). One wave per node, lanes over edges.
__launch_bounds__(256)
__global__ void agg2_k(const float* __restrict__ z, const unsigned* __restrict__ rp,
                       const unsigned* __restrict__ col, const float* __restrict__ dinv,
                       const float* __restrict__ b2, float* __restrict__ out) {
    int i = (blockIdx.x * 256 + threadIdx.x) >> 6;
    int lane = threadIdx.x & 63;
    if (i >= NN) return;

    float di = dinv[i];
    unsigned p0 = rp[i], p1 = rp[i + 1];
    float a0 = 0.f, a1 = 0.f;
    for (unsigned e = p0 + lane; e < p1; e += 64) {
        unsigned s = col[e];
        float cf = di * dinv[s];
        float2 v = ((const float2*)z)[s];
        a0 = fmaf(cf, v.x, a0);
        a1 = fmaf(cf, v.y, a1);
    }
#pragma unroll
    for (int off = 32; off > 0; off >>= 1) {
        a0 += __shfl_down(a0, off);
        a1 += __shfl_down(a1, off);
    }
    if (lane == 0) {
        float2 zi = ((const float2*)z)[i];
        out[(size_t)i * 2]     = fmaf(di * di, zi.x, a0) + b2[0];
        out[(size_t)i * 2 + 1] = fmaf(di * di, zi.y, a1) + b2[1];
    }
}

extern "C" void kernel_launch(void* const* d_in, const int* in_sizes, int n_in,
                              void* d_out, int out_size, void* d_ws, size_t ws_size,
                              hipStream_t stream) {
    const float* x  = (const float*)d_in[0];
    const int*   ei = (const int*)d_in[1];
    const float* W1 = (const float*)d_in[2];
    const float* b1 = (const float*)d_in[3];
    const float* W2 = (const float*)d_in[4];
    const float* b2 = (const float*)d_in[5];
    float* out = (float*)d_out;

    char* ws = (char*)d_ws;
    float*    h    = (float*)(ws);
    float*    z    = (float*)(ws + 51200000);
    float*    dinv = (float*)(ws + 52000000);
    unsigned* cnt  = (unsigned*)(ws + 52400000);
    unsigned* fill = (unsigned*)(ws + 52800000);
    unsigned* rp   = (unsigned*)(ws + 53200000);
    unsigned* col  = (unsigned*)(ws + 53600016);
    unsigned* bsum = (unsigned*)(ws + 60000016);

    hipMemsetAsync(cnt,  0, NN * sizeof(unsigned), stream);
    hipMemsetAsync(fill, 0, NN * sizeof(unsigned), stream);

    hist_k<<<(NE + 255) / 256, 256, 0, stream>>>(ei, cnt);
    dinv_k<<<(NN + 255) / 256, 256, 0, stream>>>(cnt, dinv);

    const int NB = (NN + 1023) / 1024;  // 98
    scan1_k<<<NB, 256, 0, stream>>>(cnt, rp, bsum);
    scan2_k<<<1, 128, 0, stream>>>(bsum, NB);
    scan3_k<<<(NN + 255) / 256, 256, 0, stream>>>(rp, bsum);

    fill_k<<<(NE + 255) / 256, 256, 0, stream>>>(ei, rp, fill, col);

    gemm1_k<<<(NN + 127) / 128, 256, 0, stream>>>(x, W1, h);
    agg1_k<<<(NN + 3) / 4, 256, 0, stream>>>(h, rp, col, dinv, b1, W2, z);
    agg2_k<<<(NN + 3) / 4, 256, 0, stream>>>(z, rp, col, dinv, b2, out);
}

// Round 3
// 345.410 us; speedup vs baseline: 1.8415x; 1.3885x over previous
//
#include <hip/hip_runtime.h>
#include <cstdint>
#include <cstddef>

#define NN 100000
#define NE 1600000
#define D 128
#define NBK 782            // ceil(NN / 128) buckets of 128 nodes
#define NBLK_P 200         // partition blocks
#define EPB 8000           // edges per partition block (200*8000 = 1.6M exact)

// ---------------- workspace layout (bytes) ----------------
// part  : NE u32      @ 0          (6,400,000)   } dead after p4_csr;
// offs  : 200*782 u32 @ 6,400,000  (  625,600)   } overlapped by h
// base  : 783 u32     @ 7,100,000  (    3,132)   }
// h     : NN*128 f32  @ 0          (51,200,000)  (written by gemm1, after CSR build)
// z     : NN*2 f32    @ 51,200,000 (   800,000)
// dinv  : NN f32      @ 52,000,000 (   400,000)
// rp    : NN+1 u32    @ 52,400,000 (   400,004)
// col   : NE u32      @ 52,800,016 ( 6,400,000)  -> total 59,200,016

// P1: per-block LDS histogram over dst buckets (no global atomics).
__launch_bounds__(256)
__global__ void p1_count_k(const int* __restrict__ ei, unsigned* __restrict__ offs) {
    __shared__ unsigned hist[NBK];
    int tid = threadIdx.x, b = blockIdx.x;
    for (int k = tid; k < NBK; k += 256) hist[k] = 0u;
    __syncthreads();
    int e0 = b * EPB;
    for (int i = tid; i < EPB; i += 256) {
        int d = ei[NE + e0 + i];
        atomicAdd(&hist[d >> 7], 1u);
    }
    __syncthreads();
    for (int k = tid; k < NBK; k += 256) offs[(size_t)b * NBK + k] = hist[k];
}

// P2a: per-bucket exclusive prefix over blocks (in place) + bucket totals -> base.
__global__ void p2a_k(unsigned* __restrict__ offs, unsigned* __restrict__ base) {
    int k = blockIdx.x * 256 + threadIdx.x;
    if (k >= NBK) return;
    unsigned run = 0;
    for (int b = 0; b < NBLK_P; b++) {
        unsigned t = offs[(size_t)b * NBK + k];
        offs[(size_t)b * NBK + k] = run;
        run += t;
    }
    base[k] = run;
}

// P2b: exclusive scan of bucket totals; base[NBK] = NE.
__global__ void p2b_k(unsigned* __restrict__ base) {
    __shared__ unsigned sh[1024];
    int t = threadIdx.x;
    unsigned v = (t < NBK) ? base[t] : 0u;
    sh[t] = v;
    __syncthreads();
    for (int off = 1; off < 1024; off <<= 1) {
        unsigned u = (t >= off) ? sh[t - off] : 0u;
        __syncthreads();
        sh[t] += u;
        __syncthreads();
    }
    if (t < NBK) base[t] = sh[t] - v;
    if (t == NBK) base[NBK] = sh[NBK - 1];
}

// P3: scatter packed edges into bucket-partitioned order via LDS running counters.
__launch_bounds__(256)
__global__ void p3_scatter_k(const int* __restrict__ ei, const unsigned* __restrict__ offs,
                             const unsigned* __restrict__ base, unsigned* __restrict__ part) {
    __shared__ unsigned lcnt[NBK];
    int tid = threadIdx.x, b = blockIdx.x;
    for (int k = tid; k < NBK; k += 256) lcnt[k] = base[k] + offs[(size_t)b * NBK + k];
    __syncthreads();
    int e0 = b * EPB;
    for (int i = tid; i < EPB; i += 256) {
        int s = ei[e0 + i];
        int d = ei[NE + e0 + i];
        unsigned pos = atomicAdd(&lcnt[d >> 7], 1u);
        part[pos] = (unsigned)s | ((unsigned)(d & 127) << 20);
    }
}

// P4: one block per bucket. Count per node in LDS, scan, emit rp/dinv, regroup col.
__launch_bounds__(256)
__global__ void p4_csr_k(const unsigned* __restrict__ part, const unsigned* __restrict__ base,
                         unsigned* __restrict__ rp, float* __restrict__ dinv,
                         unsigned* __restrict__ col) {
    __shared__ unsigned c[128], p[128], run[128];
    int tid = threadIdx.x, k = blockIdx.x;
    int n0 = k << 7;
    int nodes = (NN - n0 < 128) ? (NN - n0) : 128;
    unsigned e0 = base[k], e1 = base[k + 1];

    if (tid < 128) c[tid] = 0u;
    __syncthreads();
    for (unsigned e = e0 + tid; e < e1; e += 256)
        atomicAdd(&c[(part[e] >> 20) & 127], 1u);
    __syncthreads();

    // inclusive scan of c -> p (128 entries, first 128 threads)
    unsigned myc = (tid < 128) ? c[tid] : 0u;
    if (tid < 128) p[tid] = myc;
    __syncthreads();
    for (int off = 1; off < 128; off <<= 1) {
        unsigned u = 0;
        if (tid < 128 && tid >= off) u = p[tid - off];
        __syncthreads();
        if (tid < 128) p[tid] += u;
        __syncthreads();
    }
    if (tid < 128) {
        unsigned excl = p[tid] - myc;
        run[tid] = excl;
        if (tid < nodes) {
            rp[n0 + tid] = e0 + excl;
            dinv[n0 + tid] = rsqrtf((float)(myc + 1u));
        }
    }
    if (k == 0 && tid == 0) rp[NN] = NE;
    __syncthreads();

    for (unsigned e = e0 + tid; e < e1; e += 256) {
        unsigned v = part[e];
        unsigned dlo = (v >> 20) & 127;
        unsigned pos = e0 + atomicAdd(&run[dlo], 1u);
        col[pos] = v & 0xFFFFFu;
    }
}

__device__ inline void fma4(float4& a, float s, const float4& w) {
    a.x = fmaf(s, w.x, a.x); a.y = fmaf(s, w.y, a.y);
    a.z = fmaf(s, w.z, a.z); a.w = fmaf(s, w.w, a.w);
}

// h = x @ W1.  256 threads; tile 128 rows x 128 cols; x staged via LDS (stride 36).
__launch_bounds__(256)
__global__ void gemm1_k(const float* __restrict__ x, const float* __restrict__ W,
                        float* __restrict__ h) {
    __shared__ float xs[128 * 36];
    int tid = threadIdx.x;
    int cg = tid >> 4;
    int rg = tid & 15;
    int j0 = cg * 8;
    int rb = blockIdx.x * 128;

    float4 acc[8][2];
#pragma unroll
    for (int i = 0; i < 8; i++) { acc[i][0] = make_float4(0,0,0,0); acc[i][1] = make_float4(0,0,0,0); }

    for (int kk0 = 0; kk0 < D; kk0 += 32) {
        if (kk0) __syncthreads();
#pragma unroll
        for (int q = 0; q < 4; q++) {
            int idx = q * 256 + tid;
            int row = idx >> 3;
            int c4  = (idx & 7) * 4;
            int gr  = rb + row;
            float4 v = (gr < NN) ? *(const float4*)(x + (size_t)gr * D + kk0 + c4)
                                 : make_float4(0,0,0,0);
            *(float4*)(&xs[row * 36 + c4]) = v;
        }
        __syncthreads();

#pragma unroll
        for (int kk = 0; kk < 32; kk += 4) {
            float4 xv[8];
#pragma unroll
            for (int i = 0; i < 8; i++)
                xv[i] = *(const float4*)(&xs[(rg + 16 * i) * 36 + kk]);
#pragma unroll
            for (int t = 0; t < 4; t++) {
                const float* wr = W + (size_t)(kk0 + kk + t) * D + j0;
                float4 w0 = *(const float4*)wr;
                float4 w1 = *(const float4*)(wr + 4);
#pragma unroll
                for (int i = 0; i < 8; i++) {
                    float s = (t == 0) ? xv[i].x : (t == 1) ? xv[i].y : (t == 2) ? xv[i].z : xv[i].w;
                    fma4(acc[i][0], s, w0);
                    fma4(acc[i][1], s, w1);
                }
            }
        }
    }

#pragma unroll
    for (int i = 0; i < 8; i++) {
        int r = rb + rg + 16 * i;
        if (r < NN) {
            *(float4*)(h + (size_t)r * D + j0)     = acc[i][0];
            *(float4*)(h + (size_t)r * D + j0 + 4) = acc[i][1];
        }
    }
}

// Layer-1 aggregation fused with bias+ReLU and the 128x2 layer-2 linear.
__launch_bounds__(256)
__global__ void agg1_k(const float* __restrict__ h, const unsigned* __restrict__ rp,
                       const unsigned* __restrict__ col, const float* __restrict__ dinv,
                       const float* __restrict__ b1, const float* __restrict__ W2,
                       float* __restrict__ z) {
    int i = (blockIdx.x * 256 + threadIdx.x) >> 6;
    int lane = threadIdx.x & 63;
    if (i >= NN) return;

    float di = dinv[i];
    float2 hv = ((const float2*)(h + (size_t)i * D))[lane];
    float cself = di * di;
    float ax = cself * hv.x;
    float ay = cself * hv.y;

    unsigned p0 = rp[i], p1 = rp[i + 1];
    unsigned e = p0;
    for (; e + 4 <= p1; e += 4) {
        unsigned s0 = col[e], s1 = col[e + 1], s2 = col[e + 2], s3 = col[e + 3];
        float d0 = dinv[s0], d1 = dinv[s1], d2 = dinv[s2], d3 = dinv[s3];
        float2 v0 = ((const float2*)(h + (size_t)s0 * D))[lane];
        float2 v1 = ((const float2*)(h + (size_t)s1 * D))[lane];
        float2 v2 = ((const float2*)(h + (size_t)s2 * D))[lane];
        float2 v3 = ((const float2*)(h + (size_t)s3 * D))[lane];
        ax = fmaf(di * d0, v0.x, ax); ay = fmaf(di * d0, v0.y, ay);
        ax = fmaf(di * d1, v1.x, ax); ay = fmaf(di * d1, v1.y, ay);
        ax = fmaf(di * d2, v2.x, ax); ay = fmaf(di * d2, v2.y, ay);
        ax = fmaf(di * d3, v3.x, ax); ay = fmaf(di * d3, v3.y, ay);
    }
    for (; e < p1; ++e) {
        unsigned s = col[e];
        float cf = di * dinv[s];
        float2 v = ((const float2*)(h + (size_t)s * D))[lane];
        ax = fmaf(cf, v.x, ax);
        ay = fmaf(cf, v.y, ay);
    }

    float2 bv = ((const float2*)b1)[lane];
    float h0 = fmaxf(ax + bv.x, 0.f);
    float h1 = fmaxf(ay + bv.y, 0.f);

    float4 w = ((const float4*)W2)[lane];
    float pz0 = fmaf(h0, w.x, h1 * w.z);
    float pz1 = fmaf(h0, w.y, h1 * w.w);
#pragma unroll
    for (int off = 32; off > 0; off >>= 1) {
        pz0 += __shfl_down(pz0, off);
        pz1 += __shfl_down(pz1, off);
    }
    if (lane == 0) {
        float2* zp = (float2*)(z + (size_t)i * 2);
        *zp = make_float2(pz0, pz1);
    }
}

// Layer-2 aggregation over z (N x 2). One wave per node, lanes over edges.
__launch_bounds__(256)
__global__ void agg2_k(const float* __restrict__ z, const unsigned* __restrict__ rp,
                       const unsigned* __restrict__ col, const float* __restrict__ dinv,
                       const float* __restrict__ b2, float* __restrict__ out) {
    int i = (blockIdx.x * 256 + threadIdx.x) >> 6;
    int lane = threadIdx.x & 63;
    if (i >= NN) return;

    float di = dinv[i];
    unsigned p0 = rp[i], p1 = rp[i + 1];
    float a0 = 0.f, a1 = 0.f;
    for (unsigned e = p0 + lane; e < p1; e += 64) {
        unsigned s = col[e];
        float cf = di * dinv[s];
        float2 v = ((const float2*)z)[s];
        a0 = fmaf(cf, v.x, a0);
        a1 = fmaf(cf, v.y, a1);
    }
#pragma unroll
    for (int off = 32; off > 0; off >>= 1) {
        a0 += __shfl_down(a0, off);
        a1 += __shfl_down(a1, off);
    }
    if (lane == 0) {
        float2 zi = ((const float2*)z)[i];
        out[(size_t)i * 2]     = fmaf(di * di, zi.x, a0) + b2[0];
        out[(size_t)i * 2 + 1] = fmaf(di * di, zi.y, a1) + b2[1];
    }
}

extern "C" void kernel_launch(void* const* d_in, const int* in_sizes, int n_in,
                              void* d_out, int out_size, void* d_ws, size_t ws_size,
                              hipStream_t stream) {
    const float* x  = (const float*)d_in[0];
    const int*   ei = (const int*)d_in[1];
    const float* W1 = (const float*)d_in[2];
    const float* b1 = (const float*)d_in[3];
    const float* W2 = (const float*)d_in[4];
    const float* b2 = (const float*)d_in[5];
    float* out = (float*)d_out;

    char* ws = (char*)d_ws;
    unsigned* part = (unsigned*)(ws);               // overlaps h, dead before gemm1
    unsigned* offs = (unsigned*)(ws + 6400000);     // overlaps h
    unsigned* base = (unsigned*)(ws + 7100000);     // overlaps h
    float*    h    = (float*)(ws);
    float*    z    = (float*)(ws + 51200000);
    float*    dinv = (float*)(ws + 52000000);
    unsigned* rp   = (unsigned*)(ws + 52400000);
    unsigned* col  = (unsigned*)(ws + 52800016);

    p1_count_k<<<NBLK_P, 256, 0, stream>>>(ei, offs);
    p2a_k<<<(NBK + 255) / 256, 256, 0, stream>>>(offs, base);
    p2b_k<<<1, 1024, 0, stream>>>(base);
    p3_scatter_k<<<NBLK_P, 256, 0, stream>>>(ei, offs, base, part);
    p4_csr_k<<<NBK, 256, 0, stream>>>(part, base, rp, dinv, col);

    gemm1_k<<<(NN + 127) / 128, 256, 0, stream>>>(x, W1, h);
    agg1_k<<<(NN + 3) / 4, 256, 0, stream>>>(h, rp, col, dinv, b1, W2, z);
    agg2_k<<<(NN + 3) / 4, 256, 0, stream>>>(z, rp, col, dinv, b2, out);
}

// Round 5
// 293.163 us; speedup vs baseline: 2.1697x; 1.1782x over previous
//
#include <hip/hip_runtime.h>
#include <hip/hip_fp16.h>
#include <cstdint>
#include <cstddef>

#define NN 100000
#define NE 1600000
#define D 128
#define NBK 782            // ceil(NN / 128) buckets of 128 nodes
#define NBLK_P 200         // partition blocks
#define EPB 8000           // edges per partition block (200*8000 = 1.6M exact)

// ---------------- workspace layout (bytes) ----------------
// part  : NE u32      @ 0          (6,400,000)   } dead after p4_csr;
// offs  : 200*782 u32 @ 6,400,000  (  625,600)   } overlapped by h
// base  : 783 u32     @ 7,100,000  (    3,132)   }
// h     : NN*128 f16  @ 0          (25,600,000)  (written by gemm1, after CSR build)
// z     : NN*2 f32    @ 25,600,000 (   800,000)
// dinv  : NN f32      @ 26,400,000 (   400,000)
// rp    : NN+1 u32    @ 26,800,000 (   400,004)
// col   : NE u32      @ 27,200,016 ( 6,400,000)  -> total 33,600,016

// P1: per-block LDS histogram over dst buckets (no global atomics).
__launch_bounds__(256)
__global__ void p1_count_k(const int* __restrict__ ei, unsigned* __restrict__ offs) {
    __shared__ unsigned hist[NBK];
    int tid = threadIdx.x, b = blockIdx.x;
    for (int k = tid; k < NBK; k += 256) hist[k] = 0u;
    __syncthreads();
    int e0 = b * EPB;
    for (int i = tid; i < EPB; i += 256) {
        int d = ei[NE + e0 + i];
        atomicAdd(&hist[d >> 7], 1u);
    }
    __syncthreads();
    for (int k = tid; k < NBK; k += 256) offs[(size_t)b * NBK + k] = hist[k];
}

// P2a: block per bucket; parallel loads of the 200 per-block counts + LDS scan.
__launch_bounds__(256)
__global__ void p2a_k(unsigned* __restrict__ offs, unsigned* __restrict__ base) {
    __shared__ unsigned sh[256];
    int t = threadIdx.x, k = blockIdx.x;
    unsigned v = (t < NBLK_P) ? offs[(size_t)t * NBK + k] : 0u;
    sh[t] = v;
    __syncthreads();
    for (int off = 1; off < 256; off <<= 1) {
        unsigned u = (t >= off) ? sh[t - off] : 0u;
        __syncthreads();
        sh[t] += u;
        __syncthreads();
    }
    if (t < NBLK_P) offs[(size_t)t * NBK + k] = sh[t] - v;  // exclusive
    if (t == 255) base[k] = sh[255];                         // bucket total
}

// P2b: exclusive scan of bucket totals; base[NBK] = NE.
__global__ void p2b_k(unsigned* __restrict__ base) {
    __shared__ unsigned sh[1024];
    int t = threadIdx.x;
    unsigned v = (t < NBK) ? base[t] : 0u;
    sh[t] = v;
    __syncthreads();
    for (int off = 1; off < 1024; off <<= 1) {
        unsigned u = (t >= off) ? sh[t - off] : 0u;
        __syncthreads();
        sh[t] += u;
        __syncthreads();
    }
    if (t < NBK) base[t] = sh[t] - v;
    if (t == NBK) base[NBK] = sh[NBK - 1];
}

// P3: scatter packed edges into bucket-partitioned order via LDS running counters.
__launch_bounds__(256)
__global__ void p3_scatter_k(const int* __restrict__ ei, const unsigned* __restrict__ offs,
                             const unsigned* __restrict__ base, unsigned* __restrict__ part) {
    __shared__ unsigned lcnt[NBK];
    int tid = threadIdx.x, b = blockIdx.x;
    for (int k = tid; k < NBK; k += 256) lcnt[k] = base[k] + offs[(size_t)b * NBK + k];
    __syncthreads();
    int e0 = b * EPB;
    for (int i = tid; i < EPB; i += 256) {
        int s = ei[e0 + i];
        int d = ei[NE + e0 + i];
        unsigned pos = atomicAdd(&lcnt[d >> 7], 1u);
        part[pos] = (unsigned)s | ((unsigned)(d & 127) << 20);
    }
}

// P4: one block per bucket. Count per node in LDS, scan, emit rp/dinv, regroup col.
__launch_bounds__(256)
__global__ void p4_csr_k(const unsigned* __restrict__ part, const unsigned* __restrict__ base,
                         unsigned* __restrict__ rp, float* __restrict__ dinv,
                         unsigned* __restrict__ col) {
    __shared__ unsigned c[128], p[128], run[128];
    int tid = threadIdx.x, k = blockIdx.x;
    int n0 = k << 7;
    int nodes = (NN - n0 < 128) ? (NN - n0) : 128;
    unsigned e0 = base[k], e1 = base[k + 1];

    if (tid < 128) c[tid] = 0u;
    __syncthreads();
    for (unsigned e = e0 + tid; e < e1; e += 256)
        atomicAdd(&c[(part[e] >> 20) & 127], 1u);
    __syncthreads();

    unsigned myc = (tid < 128) ? c[tid] : 0u;
    if (tid < 128) p[tid] = myc;
    __syncthreads();
    for (int off = 1; off < 128; off <<= 1) {
        unsigned u = 0;
        if (tid < 128 && tid >= off) u = p[tid - off];
        __syncthreads();
        if (tid < 128) p[tid] += u;
        __syncthreads();
    }
    if (tid < 128) {
        unsigned excl = p[tid] - myc;
        run[tid] = excl;
        if (tid < nodes) {
            rp[n0 + tid] = e0 + excl;
            dinv[n0 + tid] = rsqrtf((float)(myc + 1u));
        }
    }
    if (k == 0 && tid == 0) rp[NN] = NE;
    __syncthreads();

    for (unsigned e = e0 + tid; e < e1; e += 256) {
        unsigned v = part[e];
        unsigned dlo = (v >> 20) & 127;
        unsigned pos = e0 + atomicAdd(&run[dlo], 1u);
        col[pos] = v & 0xFFFFFu;
    }
}

__device__ inline void fma4(float4& a, float s, const float4& w) {
    a.x = fmaf(s, w.x, a.x); a.y = fmaf(s, w.y, a.y);
    a.z = fmaf(s, w.z, a.z); a.w = fmaf(s, w.w, a.w);
}

// h = x @ W1, output fp16.  256 threads; tile 128 rows x 128 cols; x staged via LDS.
__launch_bounds__(256)
__global__ void gemm1_k(const float* __restrict__ x, const float* __restrict__ W,
                        __half* __restrict__ h) {
    __shared__ float xs[128 * 36];
    int tid = threadIdx.x;
    int cg = tid >> 4;
    int rg = tid & 15;
    int j0 = cg * 8;
    int rb = blockIdx.x * 128;

    float4 acc[8][2];
#pragma unroll
    for (int i = 0; i < 8; i++) { acc[i][0] = make_float4(0,0,0,0); acc[i][1] = make_float4(0,0,0,0); }

    for (int kk0 = 0; kk0 < D; kk0 += 32) {
        if (kk0) __syncthreads();
#pragma unroll
        for (int q = 0; q < 4; q++) {
            int idx = q * 256 + tid;
            int row = idx >> 3;
            int c4  = (idx & 7) * 4;
            int gr  = rb + row;
            float4 v = (gr < NN) ? *(const float4*)(x + (size_t)gr * D + kk0 + c4)
                                 : make_float4(0,0,0,0);
            *(float4*)(&xs[row * 36 + c4]) = v;
        }
        __syncthreads();

#pragma unroll
        for (int kk = 0; kk < 32; kk += 4) {
            float4 xv[8];
#pragma unroll
            for (int i = 0; i < 8; i++)
                xv[i] = *(const float4*)(&xs[(rg + 16 * i) * 36 + kk]);
#pragma unroll
            for (int t = 0; t < 4; t++) {
                const float* wr = W + (size_t)(kk0 + kk + t) * D + j0;
                float4 w0 = *(const float4*)wr;
                float4 w1 = *(const float4*)(wr + 4);
#pragma unroll
                for (int i = 0; i < 8; i++) {
                    float s = (t == 0) ? xv[i].x : (t == 1) ? xv[i].y : (t == 2) ? xv[i].z : xv[i].w;
                    fma4(acc[i][0], s, w0);
                    fma4(acc[i][1], s, w1);
                }
            }
        }
    }

#pragma unroll
    for (int i = 0; i < 8; i++) {
        int r = rb + rg + 16 * i;
        if (r < NN) {
            union { __half2 h2[4]; uint4 u4; } o;
            o.h2[0] = __floats2half2_rn(acc[i][0].x, acc[i][0].y);
            o.h2[1] = __floats2half2_rn(acc[i][0].z, acc[i][0].w);
            o.h2[2] = __floats2half2_rn(acc[i][1].x, acc[i][1].y);
            o.h2[3] = __floats2half2_rn(acc[i][1].z, acc[i][1].w);
            *(uint4*)(h + (size_t)r * D + j0) = o.u4;  // full 16B store (8 halves)
        }
    }
}

// Layer-1 aggregation (fp16 h rows) fused with bias+ReLU and the 128x2 layer-2 linear.
// One wave per node; lane holds 2 features (one half2). x4 edge unroll.
__launch_bounds__(256)
__global__ void agg1_k(const __half* __restrict__ h, const unsigned* __restrict__ rp,
                       const unsigned* __restrict__ col, const float* __restrict__ dinv,
                       const float* __restrict__ b1, const float* __restrict__ W2,
                       float* __restrict__ z) {
    int i = (blockIdx.x * 256 + threadIdx.x) >> 6;
    int lane = threadIdx.x & 63;
    if (i >= NN) return;

    const __half2* hb = (const __half2*)h;
    float di = dinv[i];
    float2 hv = __half22float2(hb[(size_t)i * 64 + lane]);
    float cself = di * di;
    float ax = cself * hv.x;
    float ay = cself * hv.y;

    unsigned p0 = rp[i], p1 = rp[i + 1];
    unsigned e = p0;
    for (; e + 4 <= p1; e += 4) {
        unsigned s0 = col[e], s1 = col[e + 1], s2 = col[e + 2], s3 = col[e + 3];
        float d0 = dinv[s0], d1 = dinv[s1], d2 = dinv[s2], d3 = dinv[s3];
        float2 v0 = __half22float2(hb[(size_t)s0 * 64 + lane]);
        float2 v1 = __half22float2(hb[(size_t)s1 * 64 + lane]);
        float2 v2 = __half22float2(hb[(size_t)s2 * 64 + lane]);
        float2 v3 = __half22float2(hb[(size_t)s3 * 64 + lane]);
        ax = fmaf(di * d0, v0.x, ax); ay = fmaf(di * d0, v0.y, ay);
        ax = fmaf(di * d1, v1.x, ax); ay = fmaf(di * d1, v1.y, ay);
        ax = fmaf(di * d2, v2.x, ax); ay = fmaf(di * d2, v2.y, ay);
        ax = fmaf(di * d3, v3.x, ax); ay = fmaf(di * d3, v3.y, ay);
    }
    for (; e < p1; ++e) {
        unsigned s = col[e];
        float cf = di * dinv[s];
        float2 v = __half22float2(hb[(size_t)s * 64 + lane]);
        ax = fmaf(cf, v.x, ax);
        ay = fmaf(cf, v.y, ay);
    }

    float2 bv = ((const float2*)b1)[lane];
    float h0 = fmaxf(ax + bv.x, 0.f);
    float h1 = fmaxf(ay + bv.y, 0.f);

    float4 w = ((const float4*)W2)[lane];
    float pz0 = fmaf(h0, w.x, h1 * w.z);
    float pz1 = fmaf(h0, w.y, h1 * w.w);
#pragma unroll
    for (int off = 32; off > 0; off >>= 1) {
        pz0 += __shfl_down(pz0, off);
        pz1 += __shfl_down(pz1, off);
    }
    if (lane == 0) {
        float2* zp = (float2*)(z + (size_t)i * 2);
        *zp = make_float2(pz0, pz1);
    }
}

// Layer-2 aggregation over z (N x 2). One wave per node, lanes over edges.
__launch_bounds__(256)
__global__ void agg2_k(const float* __restrict__ z, const unsigned* __restrict__ rp,
                       const unsigned* __restrict__ col, const float* __restrict__ dinv,
                       const float* __restrict__ b2, float* __restrict__ out) {
    int i = (blockIdx.x * 256 + threadIdx.x) >> 6;
    int lane = threadIdx.x & 63;
    if (i >= NN) return;

    float di = dinv[i];
    unsigned p0 = rp[i], p1 = rp[i + 1];
    float a0 = 0.f, a1 = 0.f;
    for (unsigned e = p0 + lane; e < p1; e += 64) {
        unsigned s = col[e];
        float cf = di * dinv[s];
        float2 v = ((const float2*)z)[s];
        a0 = fmaf(cf, v.x, a0);
        a1 = fmaf(cf, v.y, a1);
    }
#pragma unroll
    for (int off = 32; off > 0; off >>= 1) {
        a0 += __shfl_down(a0, off);
        a1 += __shfl_down(a1, off);
    }
    if (lane == 0) {
        float2 zi = ((const float2*)z)[i];
        out[(size_t)i * 2]     = fmaf(di * di, zi.x, a0) + b2[0];
        out[(size_t)i * 2 + 1] = fmaf(di * di, zi.y, a1) + b2[1];
    }
}

extern "C" void kernel_launch(void* const* d_in, const int* in_sizes, int n_in,
                              void* d_out, int out_size, void* d_ws, size_t ws_size,
                              hipStream_t stream) {
    const float* x  = (const float*)d_in[0];
    const int*   ei = (const int*)d_in[1];
    const float* W1 = (const float*)d_in[2];
    const float* b1 = (const float*)d_in[3];
    const float* W2 = (const float*)d_in[4];
    const float* b2 = (const float*)d_in[5];
    float* out = (float*)d_out;

    char* ws = (char*)d_ws;
    unsigned* part = (unsigned*)(ws);               // overlaps h, dead before gemm1
    unsigned* offs = (unsigned*)(ws + 6400000);     // overlaps h
    unsigned* base = (unsigned*)(ws + 7100000);     // overlaps h
    __half*   h    = (__half*)(ws);
    float*    z    = (float*)(ws + 25600000);
    float*    dinv = (float*)(ws + 26400000);
    unsigned* rp   = (unsigned*)(ws + 26800000);
    unsigned* col  = (unsigned*)(ws + 27200016);

    p1_count_k<<<NBLK_P, 256, 0, stream>>>(ei, offs);
    p2a_k<<<NBK, 256, 0, stream>>>(offs, base);
    p2b_k<<<1, 1024, 0, stream>>>(base);
    p3_scatter_k<<<NBLK_P, 256, 0, stream>>>(ei, offs, base, part);
    p4_csr_k<<<NBK, 256, 0, stream>>>(part, base, rp, dinv, col);

    gemm1_k<<<(NN + 127) / 128, 256, 0, stream>>>(x, W1, h);
    agg1_k<<<(NN + 3) / 4, 256, 0, stream>>>(h, rp, col, dinv, b1, W2, z);
    agg2_k<<<(NN + 3) / 4, 256, 0, stream>>>(z, rp, col, dinv, b2, out);
}

// Round 6
// 268.966 us; speedup vs baseline: 2.3649x; 1.0900x over previous
//
#include <hip/hip_runtime.h>
#include <hip/hip_fp16.h>
#include <cstdint>
#include <cstddef>

#define NN 100000
#define NE 1600000
#define D 128
#define NBK 782            // ceil(NN / 128) buckets of 128 nodes
#define NBLK_P 200         // partition blocks
#define EPB 8000           // edges per partition block (200*8000 = 1.6M exact)

typedef _Float16 half8 __attribute__((ext_vector_type(8)));
typedef _Float16 half4v __attribute__((ext_vector_type(4)));
typedef float f32x4 __attribute__((ext_vector_type(4)));

// ---------------- workspace layout (bytes) ----------------
// part  : NE u32      @ 0          (6,400,000)   } dead after p4_csr; overlapped by h
// offs  : 200*782 u32 @ 6,400,000  (  625,600)   }
// base  : 783 u32     @ 7,100,000  (    3,132)   }
// h'    : NN*128 f16  @ 0          (25,600,000)  = dinv[row] * (x@W1), written after CSR
// z'    : NN*2 f32    @ 25,600,000 (   800,000)  = dinv[row] * (relu(agg+b1)@W2)
// dinv  : NN f32      @ 26,400,000 (   400,000)
// rp    : NN+1 u32    @ 26,800,000 (   400,004)
// col   : NE u32      @ 27,200,016 ( 6,400,000)  -> total 33,600,016

// P1: per-block LDS histogram over dst buckets (no global atomics).
__launch_bounds__(256)
__global__ void p1_count_k(const int* __restrict__ ei, unsigned* __restrict__ offs) {
    __shared__ unsigned hist[NBK];
    int tid = threadIdx.x, b = blockIdx.x;
    for (int k = tid; k < NBK; k += 256) hist[k] = 0u;
    __syncthreads();
    int e0 = b * EPB;
    for (int i = tid; i < EPB; i += 256) {
        int d = ei[NE + e0 + i];
        atomicAdd(&hist[d >> 7], 1u);
    }
    __syncthreads();
    for (int k = tid; k < NBK; k += 256) offs[(size_t)b * NBK + k] = hist[k];
}

// P2a: block per bucket; parallel loads of the 200 per-block counts + LDS scan.
__launch_bounds__(256)
__global__ void p2a_k(unsigned* __restrict__ offs, unsigned* __restrict__ base) {
    __shared__ unsigned sh[256];
    int t = threadIdx.x, k = blockIdx.x;
    unsigned v = (t < NBLK_P) ? offs[(size_t)t * NBK + k] : 0u;
    sh[t] = v;
    __syncthreads();
    for (int off = 1; off < 256; off <<= 1) {
        unsigned u = (t >= off) ? sh[t - off] : 0u;
        __syncthreads();
        sh[t] += u;
        __syncthreads();
    }
    if (t < NBLK_P) offs[(size_t)t * NBK + k] = sh[t] - v;  // exclusive
    if (t == 255) base[k] = sh[255];                         // bucket total
}

// P2b: exclusive scan of bucket totals; base[NBK] = NE.
__global__ void p2b_k(unsigned* __restrict__ base) {
    __shared__ unsigned sh[1024];
    int t = threadIdx.x;
    unsigned v = (t < NBK) ? base[t] : 0u;
    sh[t] = v;
    __syncthreads();
    for (int off = 1; off < 1024; off <<= 1) {
        unsigned u = (t >= off) ? sh[t - off] : 0u;
        __syncthreads();
        sh[t] += u;
        __syncthreads();
    }
    if (t < NBK) base[t] = sh[t] - v;
    if (t == NBK) base[NBK] = sh[NBK - 1];
}

// P3: scatter packed edges into bucket-partitioned order via LDS running counters.
__launch_bounds__(256)
__global__ void p3_scatter_k(const int* __restrict__ ei, const unsigned* __restrict__ offs,
                             const unsigned* __restrict__ base, unsigned* __restrict__ part) {
    __shared__ unsigned lcnt[NBK];
    int tid = threadIdx.x, b = blockIdx.x;
    for (int k = tid; k < NBK; k += 256) lcnt[k] = base[k] + offs[(size_t)b * NBK + k];
    __syncthreads();
    int e0 = b * EPB;
    for (int i = tid; i < EPB; i += 256) {
        int s = ei[e0 + i];
        int d = ei[NE + e0 + i];
        unsigned pos = atomicAdd(&lcnt[d >> 7], 1u);
        part[pos] = (unsigned)s | ((unsigned)(d & 127) << 20);
    }
}

// P4: one block per bucket. Count per node in LDS, scan, emit rp/dinv, regroup col.
__launch_bounds__(256)
__global__ void p4_csr_k(const unsigned* __restrict__ part, const unsigned* __restrict__ base,
                         unsigned* __restrict__ rp, float* __restrict__ dinv,
                         unsigned* __restrict__ col) {
    __shared__ unsigned c[128], p[128], run[128];
    int tid = threadIdx.x, k = blockIdx.x;
    int n0 = k << 7;
    int nodes = (NN - n0 < 128) ? (NN - n0) : 128;
    unsigned e0 = base[k], e1 = base[k + 1];

    if (tid < 128) c[tid] = 0u;
    __syncthreads();
    for (unsigned e = e0 + tid; e < e1; e += 256)
        atomicAdd(&c[(part[e] >> 20) & 127], 1u);
    __syncthreads();

    unsigned myc = (tid < 128) ? c[tid] : 0u;
    if (tid < 128) p[tid] = myc;
    __syncthreads();
    for (int off = 1; off < 128; off <<= 1) {
        unsigned u = 0;
        if (tid < 128 && tid >= off) u = p[tid - off];
        __syncthreads();
        if (tid < 128) p[tid] += u;
        __syncthreads();
    }
    if (tid < 128) {
        unsigned excl = p[tid] - myc;
        run[tid] = excl;
        if (tid < nodes) {
            rp[n0 + tid] = e0 + excl;
            dinv[n0 + tid] = rsqrtf((float)(myc + 1u));
        }
    }
    if (k == 0 && tid == 0) rp[NN] = NE;
    __syncthreads();

    for (unsigned e = e0 + tid; e < e1; e += 256) {
        unsigned v = part[e];
        unsigned dlo = (v >> 20) & 127;
        unsigned pos = e0 + atomicAdd(&run[dlo], 1u);
        col[pos] = v & 0xFFFFFu;
    }
}

// h' = dinv ⊙ (x @ W1), fp16 output, MFMA 16x16x32 f16.
// Block: 256 thr = 4 waves; 64 rows/block; W1 staged transposed in LDS (stride 136),
// x tile staged fp16 in LDS (stride 136). Verified layouts:
//   A[m=lane&15][k=(lane>>4)*8+j], B[k][n=lane&15], C/D col=lane&15 row=(lane>>4)*4+reg.
__launch_bounds__(256)
__global__ void gemm1_k(const float* __restrict__ x, const float* __restrict__ W,
                        const float* __restrict__ dinv, _Float16* __restrict__ h) {
    __shared__ _Float16 Wt[128 * 136];  // Wt[n][k] = W[k][n]
    __shared__ _Float16 xs[64 * 136];   // xs[row][k]; reused as epilogue buffer
    int tid = threadIdx.x;
    int rb = blockIdx.x * 64;
    int w = tid >> 6, lane = tid & 63;
    int m = lane & 15, q4 = lane >> 4;

    // stage W transposed (fp32 -> fp16)
#pragma unroll
    for (int q = 0; q < 16; q++) {
        int idx = q * 256 + tid;
        int k = idx >> 5;
        int n4 = (idx & 31) * 4;
        float4 v = *(const float4*)(W + (size_t)k * 128 + n4);
        Wt[(n4 + 0) * 136 + k] = (_Float16)v.x;
        Wt[(n4 + 1) * 136 + k] = (_Float16)v.y;
        Wt[(n4 + 2) * 136 + k] = (_Float16)v.z;
        Wt[(n4 + 3) * 136 + k] = (_Float16)v.w;
    }
    // stage x tile (fp32 -> fp16), 64 rows x 128 cols
#pragma unroll
    for (int q = 0; q < 8; q++) {
        int idx = q * 256 + tid;
        int row = idx >> 5;
        int c4 = (idx & 31) * 4;
        int gr = rb + row;
        float4 v = (gr < NN) ? *(const float4*)(x + (size_t)gr * 128 + c4)
                             : make_float4(0, 0, 0, 0);
        half4v hv = { (_Float16)v.x, (_Float16)v.y, (_Float16)v.z, (_Float16)v.w };
        *(half4v*)(&xs[row * 136 + c4]) = hv;
    }
    __syncthreads();

    f32x4 acc[8];
#pragma unroll
    for (int nt = 0; nt < 8; nt++) acc[nt] = (f32x4){0.f, 0.f, 0.f, 0.f};

    const _Float16* arow = &xs[(w * 16 + m) * 136 + q4 * 8];
#pragma unroll
    for (int kc = 0; kc < 4; kc++) {
        half8 af = *(const half8*)(arow + kc * 32);
#pragma unroll
        for (int nt = 0; nt < 8; nt++) {
            half8 bf = *(const half8*)(&Wt[(nt * 16 + m) * 136 + q4 * 8 + kc * 32]);
            acc[nt] = __builtin_amdgcn_mfma_f32_16x16x32_f16(af, bf, acc[nt], 0, 0, 0);
        }
    }

    // epilogue: scale by dinv[row], fp16, stage in xs (own wave's rows), coalesced store
    float dv[4];
#pragma unroll
    for (int r = 0; r < 4; r++) {
        int ri = rb + w * 16 + q4 * 4 + r;
        dv[r] = (ri < NN) ? dinv[ri] : 0.f;
    }
#pragma unroll
    for (int nt = 0; nt < 8; nt++) {
#pragma unroll
        for (int r = 0; r < 4; r++) {
            xs[(w * 16 + q4 * 4 + r) * 136 + nt * 16 + m] = (_Float16)(acc[nt][r] * dv[r]);
        }
    }
    __syncthreads();
#pragma unroll
    for (int q = 0; q < 4; q++) {
        int idx = q * 256 + tid;
        int row = idx >> 4;
        int c8 = (idx & 15) * 8;
        int gr = rb + row;
        if (gr < NN)
            *(half8*)(h + (size_t)gr * 128 + c8) = *(const half8*)(&xs[row * 136 + c8]);
    }
}

// Layer-1 aggregation of prescaled h' + bias/ReLU + 128x2 W2 projection.
// out_agg[i] = (Σ_{s∈N(i)} h'[s] + h'[i]) * dinv[i];  z'[i] = (relu(out_agg+b1)@W2) * dinv[i]
// One wave per node; lane holds half2 (2 features). Pure load+add inner loop, x8 unroll.
__launch_bounds__(256)
__global__ void agg1_k(const _Float16* __restrict__ h, const unsigned* __restrict__ rp,
                       const unsigned* __restrict__ col, const float* __restrict__ dinv,
                       const float* __restrict__ b1, const float* __restrict__ W2,
                       float* __restrict__ z) {
    int i = (blockIdx.x * 256 + threadIdx.x) >> 6;
    int lane = threadIdx.x & 63;
    if (i >= NN) return;

    const __half2* hb = (const __half2*)h;
    float di = dinv[i];
    float2 hv = __half22float2(hb[(size_t)i * 64 + lane]);
    float ax = hv.x, ay = hv.y;  // self term h'[i]

    unsigned p0 = rp[i], p1 = rp[i + 1];
    unsigned e = p0;
    for (; e + 8 <= p1; e += 8) {
        unsigned s0 = col[e], s1 = col[e + 1], s2 = col[e + 2], s3 = col[e + 3];
        unsigned s4 = col[e + 4], s5 = col[e + 5], s6 = col[e + 6], s7 = col[e + 7];
        float2 v0 = __half22float2(hb[(size_t)s0 * 64 + lane]);
        float2 v1 = __half22float2(hb[(size_t)s1 * 64 + lane]);
        float2 v2 = __half22float2(hb[(size_t)s2 * 64 + lane]);
        float2 v3 = __half22float2(hb[(size_t)s3 * 64 + lane]);
        float2 v4 = __half22float2(hb[(size_t)s4 * 64 + lane]);
        float2 v5 = __half22float2(hb[(size_t)s5 * 64 + lane]);
        float2 v6 = __half22float2(hb[(size_t)s6 * 64 + lane]);
        float2 v7 = __half22float2(hb[(size_t)s7 * 64 + lane]);
        ax += v0.x + v1.x + v2.x + v3.x + v4.x + v5.x + v6.x + v7.x;
        ay += v0.y + v1.y + v2.y + v3.y + v4.y + v5.y + v6.y + v7.y;
    }
    for (; e < p1; ++e) {
        unsigned s = col[e];
        float2 v = __half22float2(hb[(size_t)s * 64 + lane]);
        ax += v.x;
        ay += v.y;
    }
    ax *= di;
    ay *= di;

    float2 bv = ((const float2*)b1)[lane];
    float h0 = fmaxf(ax + bv.x, 0.f);
    float h1 = fmaxf(ay + bv.y, 0.f);

    float4 w = ((const float4*)W2)[lane];
    float pz0 = fmaf(h0, w.x, h1 * w.z);
    float pz1 = fmaf(h0, w.y, h1 * w.w);
#pragma unroll
    for (int off = 32; off > 0; off >>= 1) {
        pz0 += __shfl_down(pz0, off);
        pz1 += __shfl_down(pz1, off);
    }
    if (lane == 0) {
        float2* zp = (float2*)(z + (size_t)i * 2);
        *zp = make_float2(pz0 * di, pz1 * di);  // prescale for layer-2 aggregation
    }
}

// Layer-2 aggregation over prescaled z'. out[i] = (Σ z'[s] + z'[i]) * dinv[i] + b2.
__launch_bounds__(256)
__global__ void agg2_k(const float* __restrict__ z, const unsigned* __restrict__ rp,
                       const unsigned* __restrict__ col, const float* __restrict__ dinv,
                       const float* __restrict__ b2, float* __restrict__ out) {
    int i = (blockIdx.x * 256 + threadIdx.x) >> 6;
    int lane = threadIdx.x & 63;
    if (i >= NN) return;

    float di = dinv[i];
    unsigned p0 = rp[i], p1 = rp[i + 1];
    float a0 = 0.f, a1 = 0.f;
    for (unsigned e = p0 + lane; e < p1; e += 64) {
        unsigned s = col[e];
        float2 v = ((const float2*)z)[s];
        a0 += v.x;
        a1 += v.y;
    }
#pragma unroll
    for (int off = 32; off > 0; off >>= 1) {
        a0 += __shfl_down(a0, off);
        a1 += __shfl_down(a1, off);
    }
    if (lane == 0) {
        float2 zi = ((const float2*)z)[i];
        out[(size_t)i * 2]     = (a0 + zi.x) * di + b2[0];
        out[(size_t)i * 2 + 1] = (a1 + zi.y) * di + b2[1];
    }
}

extern "C" void kernel_launch(void* const* d_in, const int* in_sizes, int n_in,
                              void* d_out, int out_size, void* d_ws, size_t ws_size,
                              hipStream_t stream) {
    const float* x  = (const float*)d_in[0];
    const int*   ei = (const int*)d_in[1];
    const float* W1 = (const float*)d_in[2];
    const float* b1 = (const float*)d_in[3];
    const float* W2 = (const float*)d_in[4];
    const float* b2 = (const float*)d_in[5];
    float* out = (float*)d_out;

    char* ws = (char*)d_ws;
    unsigned* part = (unsigned*)(ws);               // overlaps h, dead before gemm1
    unsigned* offs = (unsigned*)(ws + 6400000);     // overlaps h
    unsigned* base = (unsigned*)(ws + 7100000);     // overlaps h
    _Float16* h    = (_Float16*)(ws);
    float*    z    = (float*)(ws + 25600000);
    float*    dinv = (float*)(ws + 26400000);
    unsigned* rp   = (unsigned*)(ws + 26800000);
    unsigned* col  = (unsigned*)(ws + 27200016);

    p1_count_k<<<NBLK_P, 256, 0, stream>>>(ei, offs);
    p2a_k<<<NBK, 256, 0, stream>>>(offs, base);
    p2b_k<<<1, 1024, 0, stream>>>(base);
    p3_scatter_k<<<NBLK_P, 256, 0, stream>>>(ei, offs, base, part);
    p4_csr_k<<<NBK, 256, 0, stream>>>(part, base, rp, dinv, col);

    gemm1_k<<<(NN + 63) / 64, 256, 0, stream>>>(x, W1, dinv, h);
    agg1_k<<<(NN + 3) / 4, 256, 0, stream>>>(h, rp, col, dinv, b1, W2, z);
    agg2_k<<<(NN + 3) / 4, 256, 0, stream>>>(z, rp, col, dinv, b2, out);
}

// Round 7
// 242.747 us; speedup vs baseline: 2.6203x; 1.1080x over previous
//
#include <hip/hip_runtime.h>
#include <hip/hip_fp16.h>
#include <cstdint>
#include <cstddef>

#define NN 100000
#define NE 1600000
#define D 128
#define NBK 782            // ceil(NN / 128) buckets of 128 nodes
#define NBLK_P 200         // partition blocks
#define EPB 8000           // edges per partition block (200*8000 = 1.6M exact)

typedef _Float16 half8 __attribute__((ext_vector_type(8)));
typedef _Float16 half4v __attribute__((ext_vector_type(4)));
typedef float f32x4 __attribute__((ext_vector_type(4)));

// ---------------- workspace layout (bytes) ----------------
// part  : NE u32      @ 0          (6,400,000)   } dead after p4_csr; overlapped by h
// offs  : 200*782 u32 @ 6,400,000  (  625,600)   }
// base  : 783 u32     @ 7,100,000  (    3,132)   }
// h'    : NN*128 f16  @ 0          (25,600,000)  = dinv[row] * (x@W1), written after CSR
// z'    : NN*2 f32    @ 25,600,000 (   800,000)  = dinv[row] * (relu(agg+b1)@W2)
// dinv  : NN f32      @ 26,400,000 (   400,000)
// rp    : NN+1 u32    @ 26,800,000 (   400,004)
// col   : NE u32      @ 27,200,016 ( 6,400,000)
// Wt    : 128*128 f16 @ 33,600,016 (    32,768)  -> total 33,632,784

// P1: per-block LDS histogram over dst buckets (no global atomics).
__launch_bounds__(256)
__global__ void p1_count_k(const int* __restrict__ ei, unsigned* __restrict__ offs) {
    __shared__ unsigned hist[NBK];
    int tid = threadIdx.x, b = blockIdx.x;
    for (int k = tid; k < NBK; k += 256) hist[k] = 0u;
    __syncthreads();
    int e0 = b * EPB;
    for (int i = tid; i < EPB; i += 256) {
        int d = ei[NE + e0 + i];
        atomicAdd(&hist[d >> 7], 1u);
    }
    __syncthreads();
    for (int k = tid; k < NBK; k += 256) offs[(size_t)b * NBK + k] = hist[k];
}

// P2a: block per bucket; parallel loads of the 200 per-block counts + LDS scan.
__launch_bounds__(256)
__global__ void p2a_k(unsigned* __restrict__ offs, unsigned* __restrict__ base) {
    __shared__ unsigned sh[256];
    int t = threadIdx.x, k = blockIdx.x;
    unsigned v = (t < NBLK_P) ? offs[(size_t)t * NBK + k] : 0u;
    sh[t] = v;
    __syncthreads();
    for (int off = 1; off < 256; off <<= 1) {
        unsigned u = (t >= off) ? sh[t - off] : 0u;
        __syncthreads();
        sh[t] += u;
        __syncthreads();
    }
    if (t < NBLK_P) offs[(size_t)t * NBK + k] = sh[t] - v;  // exclusive
    if (t == 255) base[k] = sh[255];                         // bucket total
}

// P2b: exclusive scan of bucket totals; base[NBK] = NE.
__global__ void p2b_k(unsigned* __restrict__ base) {
    __shared__ unsigned sh[1024];
    int t = threadIdx.x;
    unsigned v = (t < NBK) ? base[t] : 0u;
    sh[t] = v;
    __syncthreads();
    for (int off = 1; off < 1024; off <<= 1) {
        unsigned u = (t >= off) ? sh[t - off] : 0u;
        __syncthreads();
        sh[t] += u;
        __syncthreads();
    }
    if (t < NBK) base[t] = sh[t] - v;
    if (t == NBK) base[NBK] = sh[NBK - 1];
}

// P3: scatter packed edges into bucket-partitioned order via LDS running counters.
__launch_bounds__(256)
__global__ void p3_scatter_k(const int* __restrict__ ei, const unsigned* __restrict__ offs,
                             const unsigned* __restrict__ base, unsigned* __restrict__ part) {
    __shared__ unsigned lcnt[NBK];
    int tid = threadIdx.x, b = blockIdx.x;
    for (int k = tid; k < NBK; k += 256) lcnt[k] = base[k] + offs[(size_t)b * NBK + k];
    __syncthreads();
    int e0 = b * EPB;
    for (int i = tid; i < EPB; i += 256) {
        int s = ei[e0 + i];
        int d = ei[NE + e0 + i];
        unsigned pos = atomicAdd(&lcnt[d >> 7], 1u);
        part[pos] = (unsigned)s | ((unsigned)(d & 127) << 20);
    }
}

// P4: one block per bucket. Count per node in LDS, scan, emit rp/dinv, regroup col.
__launch_bounds__(256)
__global__ void p4_csr_k(const unsigned* __restrict__ part, const unsigned* __restrict__ base,
                         unsigned* __restrict__ rp, float* __restrict__ dinv,
                         unsigned* __restrict__ col) {
    __shared__ unsigned c[128], p[128], run[128];
    int tid = threadIdx.x, k = blockIdx.x;
    int n0 = k << 7;
    int nodes = (NN - n0 < 128) ? (NN - n0) : 128;
    unsigned e0 = base[k], e1 = base[k + 1];

    if (tid < 128) c[tid] = 0u;
    __syncthreads();
    for (unsigned e = e0 + tid; e < e1; e += 256)
        atomicAdd(&c[(part[e] >> 20) & 127], 1u);
    __syncthreads();

    unsigned myc = (tid < 128) ? c[tid] : 0u;
    if (tid < 128) p[tid] = myc;
    __syncthreads();
    for (int off = 1; off < 128; off <<= 1) {
        unsigned u = 0;
        if (tid < 128 && tid >= off) u = p[tid - off];
        __syncthreads();
        if (tid < 128) p[tid] += u;
        __syncthreads();
    }
    if (tid < 128) {
        unsigned excl = p[tid] - myc;
        run[tid] = excl;
        if (tid < nodes) {
            rp[n0 + tid] = e0 + excl;
            dinv[n0 + tid] = rsqrtf((float)(myc + 1u));
        }
    }
    if (k == 0 && tid == 0) rp[NN] = NE;
    __syncthreads();

    for (unsigned e = e0 + tid; e < e1; e += 256) {
        unsigned v = part[e];
        unsigned dlo = (v >> 20) & 127;
        unsigned pos = e0 + atomicAdd(&run[dlo], 1u);
        col[pos] = v & 0xFFFFFu;
    }
}

// One-shot: Wt[n][k] = (fp16) W[k][n]. 64 KB input; tiny.
__global__ void wt_k(const float* __restrict__ W, _Float16* __restrict__ Wt) {
    int idx = blockIdx.x * 256 + threadIdx.x;   // 0..16383
    int n = idx >> 7, k = idx & 127;
    Wt[idx] = (_Float16)W[k * 128 + n];
}

// h' = dinv ⊙ (x @ W1), fp16 output, MFMA 16x16x32 f16.
// Block: 256 thr = 4 waves; 64 rows/block. Wt preloaded (fp16, transposed) —
// staged to LDS with coalesced half8 copies (conflict-free ds_write_b128).
// Verified layouts: A[m=lane&15][k=(lane>>4)*8+j], B[k][n=lane&15],
//                   C/D col=lane&15 row=(lane>>4)*4+reg.
__launch_bounds__(256)
__global__ void gemm1_k(const float* __restrict__ x, const _Float16* __restrict__ Wt,
                        const float* __restrict__ dinv, _Float16* __restrict__ h) {
    __shared__ _Float16 wt[128 * 136];  // wt[n][k]
    __shared__ _Float16 xs[64 * 136];   // xs[row][k]; reused as epilogue buffer
    int tid = threadIdx.x;
    int rb = blockIdx.x * 64;
    int w = tid >> 6, lane = tid & 63;
    int m = lane & 15, q4 = lane >> 4;

    // stage Wt: 2048 half8 chunks, coalesced global, conflict-free LDS
#pragma unroll
    for (int q = 0; q < 8; q++) {
        int idx = q * 256 + tid;          // 0..2047
        int n  = idx >> 4;
        int k8 = (idx & 15) * 8;
        *(half8*)(&wt[n * 136 + k8]) = *(const half8*)(Wt + n * 128 + k8);
    }
    // stage x tile (fp32 -> fp16), 64 rows x 128 cols
#pragma unroll
    for (int q = 0; q < 8; q++) {
        int idx = q * 256 + tid;
        int row = idx >> 5;
        int c4 = (idx & 31) * 4;
        int gr = rb + row;
        float4 v = (gr < NN) ? *(const float4*)(x + (size_t)gr * 128 + c4)
                             : make_float4(0, 0, 0, 0);
        half4v hv = { (_Float16)v.x, (_Float16)v.y, (_Float16)v.z, (_Float16)v.w };
        *(half4v*)(&xs[row * 136 + c4]) = hv;
    }
    __syncthreads();

    f32x4 acc[8];
#pragma unroll
    for (int nt = 0; nt < 8; nt++) acc[nt] = (f32x4){0.f, 0.f, 0.f, 0.f};

    const _Float16* arow = &xs[(w * 16 + m) * 136 + q4 * 8];
#pragma unroll
    for (int kc = 0; kc < 4; kc++) {
        half8 af = *(const half8*)(arow + kc * 32);
#pragma unroll
        for (int nt = 0; nt < 8; nt++) {
            half8 bf = *(const half8*)(&wt[(nt * 16 + m) * 136 + q4 * 8 + kc * 32]);
            acc[nt] = __builtin_amdgcn_mfma_f32_16x16x32_f16(af, bf, acc[nt], 0, 0, 0);
        }
    }

    // epilogue: scale by dinv[row], fp16, stage in xs, coalesced store
    float dv[4];
#pragma unroll
    for (int r = 0; r < 4; r++) {
        int ri = rb + w * 16 + q4 * 4 + r;
        dv[r] = (ri < NN) ? dinv[ri] : 0.f;
    }
    __syncthreads();  // xs re-use
#pragma unroll
    for (int nt = 0; nt < 8; nt++) {
#pragma unroll
        for (int r = 0; r < 4; r++) {
            xs[(w * 16 + q4 * 4 + r) * 136 + nt * 16 + m] = (_Float16)(acc[nt][r] * dv[r]);
        }
    }
    __syncthreads();
#pragma unroll
    for (int q = 0; q < 4; q++) {
        int idx = q * 256 + tid;
        int row = idx >> 4;
        int c8 = (idx & 15) * 8;
        int gr = rb + row;
        if (gr < NN)
            *(half8*)(h + (size_t)gr * 128 + c8) = *(const half8*)(&xs[row * 136 + c8]);
    }
}

// Layer-1 aggregation of prescaled h' + bias/ReLU + 128x2 W2 projection.
// One wave per node; lane holds half2. rp/col indices forced to SGPR so the
// per-edge col reads issue as scalar loads (constant cache, off the VMEM path).
__launch_bounds__(256)
__global__ void agg1_k(const _Float16* __restrict__ h, const unsigned* __restrict__ rp,
                       const unsigned* __restrict__ col, const float* __restrict__ dinv,
                       const float* __restrict__ b1, const float* __restrict__ W2,
                       float* __restrict__ z) {
    int i = (blockIdx.x * 256 + threadIdx.x) >> 6;
    int lane = threadIdx.x & 63;
    if (i >= NN) return;

    const __half2* hb = (const __half2*)h;
    float di = dinv[i];
    float2 hv = __half22float2(hb[(size_t)i * 64 + lane]);
    float ax = hv.x, ay = hv.y;  // self term h'[i]

    unsigned p0 = __builtin_amdgcn_readfirstlane(rp[i]);
    unsigned p1 = __builtin_amdgcn_readfirstlane(rp[i + 1]);
    unsigned e = p0;
    for (; e + 8 <= p1; e += 8) {
        unsigned s0 = __builtin_amdgcn_readfirstlane(col[e]);
        unsigned s1 = __builtin_amdgcn_readfirstlane(col[e + 1]);
        unsigned s2 = __builtin_amdgcn_readfirstlane(col[e + 2]);
        unsigned s3 = __builtin_amdgcn_readfirstlane(col[e + 3]);
        unsigned s4 = __builtin_amdgcn_readfirstlane(col[e + 4]);
        unsigned s5 = __builtin_amdgcn_readfirstlane(col[e + 5]);
        unsigned s6 = __builtin_amdgcn_readfirstlane(col[e + 6]);
        unsigned s7 = __builtin_amdgcn_readfirstlane(col[e + 7]);
        float2 v0 = __half22float2(hb[(size_t)(s0 * 64u + lane)]);
        float2 v1 = __half22float2(hb[(size_t)(s1 * 64u + lane)]);
        float2 v2 = __half22float2(hb[(size_t)(s2 * 64u + lane)]);
        float2 v3 = __half22float2(hb[(size_t)(s3 * 64u + lane)]);
        float2 v4 = __half22float2(hb[(size_t)(s4 * 64u + lane)]);
        float2 v5 = __half22float2(hb[(size_t)(s5 * 64u + lane)]);
        float2 v6 = __half22float2(hb[(size_t)(s6 * 64u + lane)]);
        float2 v7 = __half22float2(hb[(size_t)(s7 * 64u + lane)]);
        ax += v0.x + v1.x + v2.x + v3.x + v4.x + v5.x + v6.x + v7.x;
        ay += v0.y + v1.y + v2.y + v3.y + v4.y + v5.y + v6.y + v7.y;
    }
    for (; e < p1; ++e) {
        unsigned s = __builtin_amdgcn_readfirstlane(col[e]);
        float2 v = __half22float2(hb[(size_t)(s * 64u + lane)]);
        ax += v.x;
        ay += v.y;
    }
    ax *= di;
    ay *= di;

    float2 bv = ((const float2*)b1)[lane];
    float h0 = fmaxf(ax + bv.x, 0.f);
    float h1 = fmaxf(ay + bv.y, 0.f);

    float4 w = ((const float4*)W2)[lane];
    float pz0 = fmaf(h0, w.x, h1 * w.z);
    float pz1 = fmaf(h0, w.y, h1 * w.w);
#pragma unroll
    for (int off = 32; off > 0; off >>= 1) {
        pz0 += __shfl_down(pz0, off);
        pz1 += __shfl_down(pz1, off);
    }
    if (lane == 0) {
        float2* zp = (float2*)(z + (size_t)i * 2);
        *zp = make_float2(pz0 * di, pz1 * di);  // prescale for layer-2 aggregation
    }
}

// Layer-2 aggregation over prescaled z'. out[i] = (Σ z'[s] + z'[i]) * dinv[i] + b2.
__launch_bounds__(256)
__global__ void agg2_k(const float* __restrict__ z, const unsigned* __restrict__ rp,
                       const unsigned* __restrict__ col, const float* __restrict__ dinv,
                       const float* __restrict__ b2, float* __restrict__ out) {
    int i = (blockIdx.x * 256 + threadIdx.x) >> 6;
    int lane = threadIdx.x & 63;
    if (i >= NN) return;

    float di = dinv[i];
    unsigned p0 = __builtin_amdgcn_readfirstlane(rp[i]);
    unsigned p1 = __builtin_amdgcn_readfirstlane(rp[i + 1]);
    float a0 = 0.f, a1 = 0.f;
    for (unsigned e = p0 + lane; e < p1; e += 64) {
        unsigned s = col[e];
        float2 v = ((const float2*)z)[s];
        a0 += v.x;
        a1 += v.y;
    }
#pragma unroll
    for (int off = 32; off > 0; off >>= 1) {
        a0 += __shfl_down(a0, off);
        a1 += __shfl_down(a1, off);
    }
    if (lane == 0) {
        float2 zi = ((const float2*)z)[i];
        out[(size_t)i * 2]     = (a0 + zi.x) * di + b2[0];
        out[(size_t)i * 2 + 1] = (a1 + zi.y) * di + b2[1];
    }
}

extern "C" void kernel_launch(void* const* d_in, const int* in_sizes, int n_in,
                              void* d_out, int out_size, void* d_ws, size_t ws_size,
                              hipStream_t stream) {
    const float* x  = (const float*)d_in[0];
    const int*   ei = (const int*)d_in[1];
    const float* W1 = (const float*)d_in[2];
    const float* b1 = (const float*)d_in[3];
    const float* W2 = (const float*)d_in[4];
    const float* b2 = (const float*)d_in[5];
    float* out = (float*)d_out;

    char* ws = (char*)d_ws;
    unsigned* part = (unsigned*)(ws);               // overlaps h, dead before gemm1
    unsigned* offs = (unsigned*)(ws + 6400000);     // overlaps h
    unsigned* base = (unsigned*)(ws + 7100000);     // overlaps h
    _Float16* h    = (_Float16*)(ws);
    float*    z    = (float*)(ws + 25600000);
    float*    dinv = (float*)(ws + 26400000);
    unsigned* rp   = (unsigned*)(ws + 26800000);
    unsigned* col  = (unsigned*)(ws + 27200016);
    _Float16* Wt   = (_Float16*)(ws + 33600016);

    wt_k<<<64, 256, 0, stream>>>(W1, Wt);
    p1_count_k<<<NBLK_P, 256, 0, stream>>>(ei, offs);
    p2a_k<<<NBK, 256, 0, stream>>>(offs, base);
    p2b_k<<<1, 1024, 0, stream>>>(base);
    p3_scatter_k<<<NBLK_P, 256, 0, stream>>>(ei, offs, base, part);
    p4_csr_k<<<NBK, 256, 0, stream>>>(part, base, rp, dinv, col);

    gemm1_k<<<(NN + 63) / 64, 256, 0, stream>>>(x, Wt, dinv, h);
    agg1_k<<<(NN + 3) / 4, 256, 0, stream>>>(h, rp, col, dinv, b1, W2, z);
    agg2_k<<<(NN + 3) / 4, 256, 0, stream>>>(z, rp, col, dinv, b2, out);
}